// Round 4
// baseline (44367.551 us; speedup 1.0000x reference)
//
#include <hip/hip_runtime.h>

// StoichNet fused forward, fp32 baseline.
// N=262144 elems, C=65536 reactions, H=4 heads.
// DIMS = [328, 256, 256, 256, 256, 128, 128, 64], res layers at 0,4,6.

constexpr int NN  = 262144;
constexpr int CC  = 65536;
constexpr int TM  = 32;    // rows per block
constexpr int BLK = 256;   // threads per block

// ---- order-preserving float<->uint encoding for atomicMax on float ----
__device__ __forceinline__ unsigned fenc(float f) {
  unsigned u = __float_as_uint(f);
  return (u & 0x80000000u) ? ~u : (u | 0x80000000u);
}
__device__ __forceinline__ float fdec(unsigned u) {
  return (u & 0x80000000u) ? __uint_as_float(u & 0x7fffffffu)
                           : __uint_as_float(~u);
}

// ---- generic dense layer: out = relu(in @ W^T + b) + res ----
// in  : LDS [TM][DIN], out : LDS [TM][DOUT]
// res = rw @ in (HAS_RW) or identity (DIN==DOUT)
template<int DIN, int DOUT, bool HAS_RW>
__device__ __forceinline__ void dense_layer(
    const float* __restrict__ w, const float* __restrict__ bvec,
    const float* __restrict__ rw, const float* in, float* out)
{
  constexpr int COLS = 4;
  constexpr int CG   = DOUT / COLS;   // col groups (64 / 32 / 16)
  constexpr int RG   = BLK / CG;      // row groups (4 / 8 / 16)
  constexpr int ROWS = TM / RG;       // rows per thread (8 / 4 / 2)
  const int t  = threadIdx.x;
  const int o0 = (t % CG) * COLS;
  int r0 = (t / CG) * ROWS;
  if constexpr (CG >= 64) r0 = __builtin_amdgcn_readfirstlane(r0); // wave-uniform

  float acc[ROWS][COLS];
  float accr[ROWS][COLS];
#pragma unroll
  for (int r = 0; r < ROWS; ++r)
#pragma unroll
    for (int c = 0; c < COLS; ++c) { acc[r][c] = 0.f; accr[r][c] = 0.f; }

  for (int k = 0; k < DIN; k += 4) {
    float4 wv[COLS], rv[COLS];
#pragma unroll
    for (int c = 0; c < COLS; ++c) {
      wv[c] = *(const float4*)(w + (size_t)(o0 + c) * DIN + k);
      if (HAS_RW) rv[c] = *(const float4*)(rw + (size_t)(o0 + c) * DIN + k);
    }
#pragma unroll
    for (int r = 0; r < ROWS; ++r) {
      float4 hv = *(const float4*)(in + (r0 + r) * DIN + k);
#pragma unroll
      for (int c = 0; c < COLS; ++c) {
        acc[r][c] += wv[c].x * hv.x + wv[c].y * hv.y + wv[c].z * hv.z + wv[c].w * hv.w;
        if (HAS_RW)
          accr[r][c] += rv[c].x * hv.x + rv[c].y * hv.y + rv[c].z * hv.z + rv[c].w * hv.w;
      }
    }
  }
  const float4 bv = *(const float4*)(bvec + o0);
#pragma unroll
  for (int r = 0; r < ROWS; ++r) {
    float4 res;
    if (!HAS_RW) {
      res = *(const float4*)(in + (r0 + r) * DIN + o0);   // identity (DIN==DOUT)
    } else {
      res.x = accr[r][0]; res.y = accr[r][1]; res.z = accr[r][2]; res.w = accr[r][3];
    }
    float4 ov;
    ov.x = fmaxf(acc[r][0] + bv.x, 0.f) + res.x;
    ov.y = fmaxf(acc[r][1] + bv.y, 0.f) + res.y;
    ov.z = fmaxf(acc[r][2] + bv.z, 0.f) + res.z;
    ov.w = fmaxf(acc[r][3] + bv.w, 0.f) + res.w;
    *(float4*)(out + (r0 + r) * DOUT + o0) = ov;
  }
}

// ---- layer 0: fea = concat(orig[n] (200), embed[idx[n]] (128)), 328 -> 256 ----
// streams fea from global via wave-uniform (scalar) loads; out to LDS
__device__ __forceinline__ void layer0(
    const float* __restrict__ orig, const float* __restrict__ embed,
    const int* sidx, int n0,
    const float* __restrict__ w, const float* __restrict__ bvec,
    const float* __restrict__ rw, float* out)
{
  constexpr int DIN = 328, COLS = 4, CG = 64, ROWS = 8;
  const int t  = threadIdx.x;
  const int o0 = (t % CG) * COLS;
  const int r0 = __builtin_amdgcn_readfirstlane((t / CG) * ROWS);

  const float* prow[ROWS];
  const float* erow[ROWS];
#pragma unroll
  for (int r = 0; r < ROWS; ++r) {
    int n = __builtin_amdgcn_readfirstlane(n0 + r0 + r);
    prow[r] = orig + (size_t)n * 200;
    erow[r] = embed + (size_t)__builtin_amdgcn_readfirstlane(sidx[r0 + r]) * 128;
  }

  float acc[ROWS][COLS];
  float accr[ROWS][COLS];
#pragma unroll
  for (int r = 0; r < ROWS; ++r)
#pragma unroll
    for (int c = 0; c < COLS; ++c) { acc[r][c] = 0.f; accr[r][c] = 0.f; }

  // orig part: k = 0..199
  for (int k = 0; k < 200; k += 4) {
    float4 wv[COLS], rv[COLS];
#pragma unroll
    for (int c = 0; c < COLS; ++c) {
      wv[c] = *(const float4*)(w  + (size_t)(o0 + c) * DIN + k);
      rv[c] = *(const float4*)(rw + (size_t)(o0 + c) * DIN + k);
    }
#pragma unroll
    for (int r = 0; r < ROWS; ++r) {
      float4 hv = *(const float4*)(prow[r] + k);
#pragma unroll
      for (int c = 0; c < COLS; ++c) {
        acc[r][c]  += wv[c].x * hv.x + wv[c].y * hv.y + wv[c].z * hv.z + wv[c].w * hv.w;
        accr[r][c] += rv[c].x * hv.x + rv[c].y * hv.y + rv[c].z * hv.z + rv[c].w * hv.w;
      }
    }
  }
  // embed part: k = 200..327
  for (int k = 0; k < 128; k += 4) {
    float4 wv[COLS], rv[COLS];
#pragma unroll
    for (int c = 0; c < COLS; ++c) {
      wv[c] = *(const float4*)(w  + (size_t)(o0 + c) * DIN + 200 + k);
      rv[c] = *(const float4*)(rw + (size_t)(o0 + c) * DIN + 200 + k);
    }
#pragma unroll
    for (int r = 0; r < ROWS; ++r) {
      float4 hv = *(const float4*)(erow[r] + k);
#pragma unroll
      for (int c = 0; c < COLS; ++c) {
        acc[r][c]  += wv[c].x * hv.x + wv[c].y * hv.y + wv[c].z * hv.z + wv[c].w * hv.w;
        accr[r][c] += rv[c].x * hv.x + rv[c].y * hv.y + rv[c].z * hv.z + rv[c].w * hv.w;
      }
    }
  }
  const float4 bv = *(const float4*)(bvec + o0);
#pragma unroll
  for (int r = 0; r < ROWS; ++r) {
    float4 ov;
    ov.x = fmaxf(acc[r][0] + bv.x, 0.f) + accr[r][0];
    ov.y = fmaxf(acc[r][1] + bv.y, 0.f) + accr[r][1];
    ov.z = fmaxf(acc[r][2] + bv.z, 0.f) + accr[r][2];
    ov.w = fmaxf(acc[r][3] + bv.w, 0.f) + accr[r][3];
    *(float4*)(out + (r0 + r) * 256 + o0) = ov;
  }
}

__global__ __launch_bounds__(BLK) void mlp_kernel(
    const float* __restrict__ orig, const int* __restrict__ ridx,
    const float* __restrict__ embed,
    const float* __restrict__ w0, const float* __restrict__ b0,
    const float* __restrict__ w1, const float* __restrict__ b1,
    const float* __restrict__ w2, const float* __restrict__ b2,
    const float* __restrict__ w3, const float* __restrict__ b3,
    const float* __restrict__ w4, const float* __restrict__ b4,
    const float* __restrict__ w5, const float* __restrict__ b5,
    const float* __restrict__ w6, const float* __restrict__ b6,
    const float* __restrict__ rw0, const float* __restrict__ rw4,
    const float* __restrict__ rw6,
    const float* __restrict__ wout, const float* __restrict__ bout,
    float* __restrict__ gate, unsigned* __restrict__ mmax)
{
  __shared__ float bufA[TM * 256];
  __shared__ float bufB[TM * 256];
  const int t  = threadIdx.x;
  const int n0 = blockIdx.x * TM;

  for (int head = 0; head < 4; ++head) {
    __syncthreads();                       // bufB free (prev head gate done)
    if (t < TM) ((int*)bufA)[t] = ridx[n0 + t];
    __syncthreads();

    layer0(orig, embed, (const int*)bufA, n0,
           w0 + head * 256 * 328, b0 + head * 256, rw0 + head * 256 * 328, bufB);
    __syncthreads();
    dense_layer<256, 256, false>(w1 + head * 256 * 256, b1 + head * 256, nullptr, bufB, bufA);
    __syncthreads();
    dense_layer<256, 256, false>(w2 + head * 256 * 256, b2 + head * 256, nullptr, bufA, bufB);
    __syncthreads();
    dense_layer<256, 256, false>(w3 + head * 256 * 256, b3 + head * 256, nullptr, bufB, bufA);
    __syncthreads();
    dense_layer<256, 128, true >(w4 + head * 128 * 256, b4 + head * 128,
                                 rw4 + head * 128 * 256, bufA, bufB);
    __syncthreads();
    dense_layer<128, 128, false>(w5 + head * 128 * 128, b5 + head * 128, nullptr, bufB, bufA);
    __syncthreads();
    dense_layer<128, 64, true >(w6 + head * 64 * 128, b6 + head * 64,
                                rw6 + head * 64 * 128, bufA, bufB);
    __syncthreads();

    // gate = wout . h + bout ; h = bufB [32][64]
    {
      const int r = t >> 3, p = t & 7;
      float s = 0.f;
#pragma unroll
      for (int j = 0; j < 8; ++j)
        s += bufB[r * 64 + p * 8 + j] * wout[head * 64 + p * 8 + j];
      s += __shfl_xor(s, 1);
      s += __shfl_xor(s, 2);
      s += __shfl_xor(s, 4);
      if (p == 0) {
        float g = s + bout[head];
        int n = n0 + r;
        gate[(size_t)n * 4 + head] = g;
        atomicMax(mmax + (size_t)ridx[n] * 4 + head, fenc(g));
      }
    }
  }
}

// pass 2: e = exp(g - m[seg]); accumulate denom
__global__ __launch_bounds__(BLK) void sm_pass2(
    const int* __restrict__ ridx, const unsigned* __restrict__ mmax,
    float* __restrict__ gate, float* __restrict__ denom)
{
  int tt = blockIdx.x * BLK + threadIdx.x;     // over N*H
  int n = tt >> 2, h = tt & 3;
  float g = gate[tt];
  int c = ridx[n];
  float m = fdec(mmax[(size_t)c * 4 + h]);
  float e = expf(g - m);
  gate[tt] = e;
  atomicAdd(denom + (size_t)c * 4 + h, e);
}

// pass 3: out[n] = mean_h e / (denom + 1e-13)
__global__ __launch_bounds__(BLK) void sm_finalize(
    const int* __restrict__ ridx, const float* __restrict__ gate,
    const float* __restrict__ denom, float* __restrict__ out)
{
  int n = blockIdx.x * BLK + threadIdx.x;
  float4 e4 = *(const float4*)(gate + (size_t)n * 4);
  int c = ridx[n];
  float4 d4 = *(const float4*)(denom + (size_t)c * 4);
  out[n] = 0.25f * (e4.x / (d4.x + 1e-13f) + e4.y / (d4.y + 1e-13f) +
                    e4.z / (d4.z + 1e-13f) + e4.w / (d4.w + 1e-13f));
}

extern "C" void kernel_launch(void* const* d_in, const int* in_sizes, int n_in,
                              void* d_out, int out_size, void* d_ws, size_t ws_size,
                              hipStream_t stream) {
  (void)in_sizes; (void)n_in; (void)out_size; (void)ws_size;
  const float* orig  = (const float*)d_in[0];
  const int*   ridx  = (const int*)d_in[1];
  const float* embed = (const float*)d_in[2];
  const float* w0 = (const float*)d_in[3];  const float* b0 = (const float*)d_in[4];
  const float* w1 = (const float*)d_in[5];  const float* b1 = (const float*)d_in[6];
  const float* w2 = (const float*)d_in[7];  const float* b2 = (const float*)d_in[8];
  const float* w3 = (const float*)d_in[9];  const float* b3 = (const float*)d_in[10];
  const float* w4 = (const float*)d_in[11]; const float* b4 = (const float*)d_in[12];
  const float* w5 = (const float*)d_in[13]; const float* b5 = (const float*)d_in[14];
  const float* w6 = (const float*)d_in[15]; const float* b6 = (const float*)d_in[16];
  const float* rw0 = (const float*)d_in[17];
  const float* rw4 = (const float*)d_in[18];
  const float* rw6 = (const float*)d_in[19];
  const float* wout = (const float*)d_in[20];
  const float* bout = (const float*)d_in[21];

  // workspace layout: gate (N*H f32, 4MB) | mmax (C*H u32, 1MB) | denom (C*H f32, 1MB)
  float*    gate  = (float*)d_ws;
  unsigned* mmax  = (unsigned*)((char*)d_ws + (size_t)NN * 4 * sizeof(float));
  float*    denom = (float*)((char*)d_ws + (size_t)NN * 4 * sizeof(float)
                                          + (size_t)CC * 4 * sizeof(unsigned));

  hipMemsetAsync(mmax, 0, (size_t)CC * 4 * sizeof(unsigned), stream);  // fenc(-inf) identity
  hipMemsetAsync(denom, 0, (size_t)CC * 4 * sizeof(float), stream);

  mlp_kernel<<<NN / TM, BLK, 0, stream>>>(
      orig, ridx, embed,
      w0, b0, w1, b1, w2, b2, w3, b3, w4, b4, w5, b5, w6, b6,
      rw0, rw4, rw6, wout, bout, gate, mmax);

  sm_pass2<<<NN * 4 / BLK, BLK, 0, stream>>>(ridx, mmax, gate, denom);
  sm_finalize<<<NN / BLK, BLK, 0, stream>>>(ridx, gate, denom, (float*)d_out);
}

// Round 5
// 5914.529 us; speedup vs baseline: 7.5015x; 7.5015x over previous
//
#include <hip/hip_runtime.h>

// StoichNet fused forward — fp16 hi/lo split MFMA version.
// N=262144 elems, C=65536 reactions, H=4 heads.
// DIMS = [328, 256, 256, 256, 256, 128, 128, 64], res layers at 0,4,6.

constexpr int NN  = 262144;
constexpr int CC  = 65536;
constexpr int TM  = 64;    // rows per block (4 waves x 16 rows)
constexpr int BLK = 256;

typedef _Float16 f16x8 __attribute__((ext_vector_type(8)));
typedef float    f32x4 __attribute__((ext_vector_type(4)));

// packed-weight geometry: per (head, job): [ct][ks][plane(hi|lo)][lane][16B]
// job frag count = (DOUT/16) * NK, frag = 2048 B (1KB hi + 1KB lo)
constexpr size_t OFF_W0  = 0;
constexpr size_t OFF_RW0 = 360448;
constexpr size_t OFF_W1  = 720896;
constexpr size_t OFF_W2  = 983040;
constexpr size_t OFF_W3  = 1245184;
constexpr size_t OFF_W4  = 1507328;
constexpr size_t OFF_RW4 = 1638400;
constexpr size_t OFF_W5  = 1769472;
constexpr size_t OFF_W6  = 1835008;
constexpr size_t OFF_RW6 = 1867776;
constexpr size_t HSTRIDE = 1900544;

__device__ __forceinline__ unsigned fenc(float f) {
  unsigned u = __float_as_uint(f);
  return (u & 0x80000000u) ? ~u : (u | 0x80000000u);
}
__device__ __forceinline__ float fdec(unsigned u) {
  return (u & 0x80000000u) ? __uint_as_float(u & 0x7fffffffu)
                           : __uint_as_float(~u);
}

// ---------------- weight pre-pack (runs every launch) ----------------
__global__ __launch_bounds__(256) void pack_kernel(
    const float* __restrict__ w0, const float* __restrict__ rw0,
    const float* __restrict__ w1, const float* __restrict__ w2,
    const float* __restrict__ w3, const float* __restrict__ w4,
    const float* __restrict__ rw4, const float* __restrict__ w5,
    const float* __restrict__ w6, const float* __restrict__ rw6,
    char* __restrict__ packed)
{
  const int job = blockIdx.y, head = blockIdx.z;
  const float* src; int DIN, DOUT, NK; size_t off;
  switch (job) {
    case 0: src = w0;  DIN = 328; DOUT = 256; NK = 11; off = OFF_W0;  break;
    case 1: src = rw0; DIN = 328; DOUT = 256; NK = 11; off = OFF_RW0; break;
    case 2: src = w1;  DIN = 256; DOUT = 256; NK = 8;  off = OFF_W1;  break;
    case 3: src = w2;  DIN = 256; DOUT = 256; NK = 8;  off = OFF_W2;  break;
    case 4: src = w3;  DIN = 256; DOUT = 256; NK = 8;  off = OFF_W3;  break;
    case 5: src = w4;  DIN = 256; DOUT = 128; NK = 8;  off = OFF_W4;  break;
    case 6: src = rw4; DIN = 256; DOUT = 128; NK = 8;  off = OFF_RW4; break;
    case 7: src = w5;  DIN = 128; DOUT = 128; NK = 4;  off = OFF_W5;  break;
    case 8: src = w6;  DIN = 128; DOUT = 64;  NK = 4;  off = OFF_W6;  break;
    default: src = rw6; DIN = 128; DOUT = 64; NK = 4;  off = OFF_RW6; break;
  }
  const int nct = DOUT >> 4;
  const int tid = blockIdx.x * 256 + threadIdx.x;
  if (tid >= nct * NK * 64) return;
  const int l = tid & 63, fs = tid >> 6;
  const int ks = fs % NK, ct = fs / NK;
  const int o  = ct * 16 + (l & 15);
  const int kb = ks * 32 + (l >> 4) * 8;
  float a[8];
  if (kb < DIN) {
    const float* p = src + (size_t)head * DOUT * DIN + (size_t)o * DIN + kb;
#pragma unroll
    for (int j = 0; j < 8; ++j) a[j] = p[j];
  } else {
#pragma unroll
    for (int j = 0; j < 8; ++j) a[j] = 0.f;
  }
  f16x8 hi, lo;
#pragma unroll
  for (int j = 0; j < 8; ++j) {
    _Float16 h = (_Float16)a[j];
    hi[j] = h;
    lo[j] = (_Float16)(a[j] - (float)h);
  }
  char* dst = packed + (size_t)head * HSTRIDE + off + (size_t)fs * 2048 + l * 16;
  *(f16x8*)dst = hi;
  *(f16x8*)(dst + 1024) = lo;
}

// ---------------- MLP kernel helpers ----------------
__device__ __forceinline__ void stage_chunk(const char* src, char* dst) {
  __builtin_amdgcn_global_load_lds(
      (const __attribute__((address_space(1))) unsigned int*)src,
      (__attribute__((address_space(3))) unsigned int*)dst, 16, 0, 0);
}

template<int NCT, int NK>
__device__ __forceinline__ void stage_ks(const char* packB, char* dst,
                                         int ks, int lane, int wv) {
  constexpr int CH = NCT * 2;   // 1 KB chunks per k-step
#pragma unroll
  for (int j = 0; j < CH / 4; ++j) {
    const int i  = j * 4 + wv;
    const int ct = i >> 1, p = i & 1;
    const char* src = packB + (size_t)(ct * NK + ks) * 2048 + p * 1024 + (size_t)lane * 16;
    stage_chunk(src, dst + i * 1024);
  }
}

template<bool GA>
__device__ __forceinline__ void load_a(
    const float* actw, const float* orig, const float* embed,
    int n, int e, int ks, int lane, f16x8& Ah, f16x8& Al)
{
  float a[8];
  if constexpr (GA) {
    const int q = lane >> 4;
    const int g = ks * 4 + q;
    if (g <= 24) {
      const float* p = orig + (size_t)n * 200 + g * 8;
#pragma unroll
      for (int j = 0; j < 8; ++j) a[j] = p[j];
    } else if (g <= 40) {
      const float* p = embed + (size_t)e * 128 + (g - 25) * 8;
#pragma unroll
      for (int j = 0; j < 8; ++j) a[j] = p[j];
    } else {
#pragma unroll
      for (int j = 0; j < 8; ++j) a[j] = 0.f;
    }
  } else {
    const int m  = lane & 15;
    const int c0 = ks * 8 + (lane >> 4) * 2;
    const int i0 = m * 256 + ((c0 ^ (m & 7)) << 2);
    f32x4 x0 = *(const f32x4*)(actw + i0);
    f32x4 x1 = *(const f32x4*)(actw + (i0 ^ 4));
    a[0] = x0[0]; a[1] = x0[1]; a[2] = x0[2]; a[3] = x0[3];
    a[4] = x1[0]; a[5] = x1[1]; a[6] = x1[2]; a[7] = x1[3];
  }
#pragma unroll
  for (int j = 0; j < 8; ++j) {
    _Float16 h = (_Float16)a[j];
    Ah[j] = h;
    Al[j] = (_Float16)(a[j] - (float)h);
  }
}

template<int NCT, int NK, bool GA>
__device__ __forceinline__ void sweep(
    const char* packB, const float* actw, char* stg,
    const float* orig, const float* embed, int n, int e,
    int lane, int wv, f32x4 acc[NCT])
{
  stage_ks<NCT, NK>(packB, stg, 0, lane, wv);
  __syncthreads();
  int buf = 0;
  for (int ks = 0; ks < NK; ++ks) {
    if (ks + 1 < NK)
      stage_ks<NCT, NK>(packB, stg + (buf ^ 1) * 32768, ks + 1, lane, wv);
    f16x8 Ah, Al;
    load_a<GA>(actw, orig, embed, n, e, ks, lane, Ah, Al);
    const char* base = stg + buf * 32768;
#pragma unroll
    for (int ct = 0; ct < NCT; ++ct) {
      const char* f = base + ct * 2048 + lane * 16;
      f16x8 Bh = *(const f16x8*)f;
      f16x8 Bl = *(const f16x8*)(f + 1024);
      acc[ct] = __builtin_amdgcn_mfma_f32_16x16x32_f16(Ah, Bh, acc[ct], 0, 0, 0);
      acc[ct] = __builtin_amdgcn_mfma_f32_16x16x32_f16(Ah, Bl, acc[ct], 0, 0, 0);
      acc[ct] = __builtin_amdgcn_mfma_f32_16x16x32_f16(Al, Bh, acc[ct], 0, 0, 0);
    }
    __syncthreads();   // drains vmcnt (stage) + lgkm, releases buffers
    buf ^= 1;
  }
}

// epilogue: relu(acc + b) + res ; res = accr (RW) or in-place identity read
template<int NCT, bool RW>
__device__ __forceinline__ void epilogue(
    f32x4 acc[NCT], f32x4 accr[NCT], const float* bias,
    float* actw, int lane)
{
#pragma unroll
  for (int ct = 0; ct < NCT; ++ct) {
    const int col = ct * 16 + (lane & 15);
    const float b = bias[col];
#pragma unroll
    for (int jr = 0; jr < 4; ++jr) {
      const int row = (lane >> 4) * 4 + jr;
      const int fi  = row * 256 + (((col >> 2) ^ (row & 7)) << 2) + (col & 3);
      float v = fmaxf(acc[ct][jr] + b, 0.f);
      if (RW) v += accr[ct][jr];
      else    v += actw[fi];
      actw[fi] = v;
    }
  }
}

__global__ __launch_bounds__(BLK, 1) void mlp_kernel(
    const float* __restrict__ orig, const int* __restrict__ ridx,
    const float* __restrict__ embed, const char* __restrict__ packed,
    const float* __restrict__ b0, const float* __restrict__ b1,
    const float* __restrict__ b2, const float* __restrict__ b3,
    const float* __restrict__ b4, const float* __restrict__ b5,
    const float* __restrict__ b6,
    const float* __restrict__ wout, const float* __restrict__ bout,
    float* __restrict__ gate, unsigned* __restrict__ mmax)
{
  extern __shared__ char smem[];
  float* act = (float*)smem;          // [64][256] fp32, XOR-chunk layout
  char*  stg = smem + 65536;          // [2][32768] staged weight frags
  const int t    = threadIdx.x;
  const int lane = t & 63;
  const int wv   = t >> 6;
  const int n0   = blockIdx.x * TM;
  float* actw = act + wv * (16 * 256);
  const int m = lane & 15, q = lane >> 4;
  const int n = n0 + wv * 16 + m;     // this lane's A-row
  const int e = ridx[n];
  const f32x4 Z4 = {0.f, 0.f, 0.f, 0.f};

  for (int head = 0; head < 4; ++head) {
    const char* pk = packed + (size_t)head * HSTRIDE;
    {
      f32x4 accr[16], acc[16];
#pragma unroll
      for (int i = 0; i < 16; ++i) { accr[i] = Z4; acc[i] = Z4; }
      sweep<16, 11, true>(pk + OFF_RW0, actw, stg, orig, embed, n, e, lane, wv, accr);
      sweep<16, 11, true>(pk + OFF_W0,  actw, stg, orig, embed, n, e, lane, wv, acc);
      epilogue<16, true>(acc, accr, b0 + head * 256, actw, lane);
    }
    {
      f32x4 acc[16];
#pragma unroll
      for (int i = 0; i < 16; ++i) acc[i] = Z4;
      sweep<16, 8, false>(pk + OFF_W1, actw, stg, orig, embed, n, e, lane, wv, acc);
      epilogue<16, false>(acc, acc, b1 + head * 256, actw, lane);
    }
    {
      f32x4 acc[16];
#pragma unroll
      for (int i = 0; i < 16; ++i) acc[i] = Z4;
      sweep<16, 8, false>(pk + OFF_W2, actw, stg, orig, embed, n, e, lane, wv, acc);
      epilogue<16, false>(acc, acc, b2 + head * 256, actw, lane);
    }
    {
      f32x4 acc[16];
#pragma unroll
      for (int i = 0; i < 16; ++i) acc[i] = Z4;
      sweep<16, 8, false>(pk + OFF_W3, actw, stg, orig, embed, n, e, lane, wv, acc);
      epilogue<16, false>(acc, acc, b3 + head * 256, actw, lane);
    }
    {
      f32x4 accr[8], acc[8];
#pragma unroll
      for (int i = 0; i < 8; ++i) { accr[i] = Z4; acc[i] = Z4; }
      sweep<8, 8, false>(pk + OFF_RW4, actw, stg, orig, embed, n, e, lane, wv, accr);
      sweep<8, 8, false>(pk + OFF_W4,  actw, stg, orig, embed, n, e, lane, wv, acc);
      epilogue<8, true>(acc, accr, b4 + head * 128, actw, lane);
    }
    {
      f32x4 acc[8];
#pragma unroll
      for (int i = 0; i < 8; ++i) acc[i] = Z4;
      sweep<8, 4, false>(pk + OFF_W5, actw, stg, orig, embed, n, e, lane, wv, acc);
      epilogue<8, false>(acc, acc, b5 + head * 128, actw, lane);
    }
    {
      f32x4 accr[4], acc[4];
#pragma unroll
      for (int i = 0; i < 4; ++i) { accr[i] = Z4; acc[i] = Z4; }
      sweep<4, 4, false>(pk + OFF_RW6, actw, stg, orig, embed, n, e, lane, wv, accr);
      sweep<4, 4, false>(pk + OFF_W6,  actw, stg, orig, embed, n, e, lane, wv, acc);
      // L6 epilogue + gate, fully in registers
      float g[4] = {0.f, 0.f, 0.f, 0.f};
#pragma unroll
      for (int ct = 0; ct < 4; ++ct) {
        const int col = ct * 16 + m;
        const float bb = b6[head * 64 + col];
        const float wo = wout[head * 64 + col];
#pragma unroll
        for (int jr = 0; jr < 4; ++jr) {
          float v = fmaxf(acc[ct][jr] + bb, 0.f) + accr[ct][jr];
          g[jr] += v * wo;
        }
      }
#pragma unroll
      for (int jr = 0; jr < 4; ++jr) {
        g[jr] += __shfl_xor(g[jr], 1);
        g[jr] += __shfl_xor(g[jr], 2);
        g[jr] += __shfl_xor(g[jr], 4);
        g[jr] += __shfl_xor(g[jr], 8);
      }
      if (m == 0) {
        const float bo = bout[head];
#pragma unroll
        for (int jr = 0; jr < 4; ++jr) {
          const int nn = n0 + wv * 16 + q * 4 + jr;
          const float gg = g[jr] + bo;
          gate[(size_t)nn * 4 + head] = gg;
          atomicMax(mmax + (size_t)ridx[nn] * 4 + head, fenc(gg));
        }
      }
    }
  }
}

// ---------------- segment softmax tail ----------------
__global__ __launch_bounds__(BLK) void sm_pass2(
    const int* __restrict__ ridx, const unsigned* __restrict__ mmax,
    float* __restrict__ gate, float* __restrict__ denom)
{
  int tt = blockIdx.x * BLK + threadIdx.x;
  int n = tt >> 2, h = tt & 3;
  float g = gate[tt];
  int c = ridx[n];
  float mm = fdec(mmax[(size_t)c * 4 + h]);
  float ev = expf(g - mm);
  gate[tt] = ev;
  atomicAdd(denom + (size_t)c * 4 + h, ev);
}

__global__ __launch_bounds__(BLK) void sm_finalize(
    const int* __restrict__ ridx, const float* __restrict__ gate,
    const float* __restrict__ denom, float* __restrict__ out)
{
  int n = blockIdx.x * BLK + threadIdx.x;
  float4 e4 = *(const float4*)(gate + (size_t)n * 4);
  int c = ridx[n];
  float4 d4 = *(const float4*)(denom + (size_t)c * 4);
  out[n] = 0.25f * (e4.x / (d4.x + 1e-13f) + e4.y / (d4.y + 1e-13f) +
                    e4.z / (d4.z + 1e-13f) + e4.w / (d4.w + 1e-13f));
}

extern "C" void kernel_launch(void* const* d_in, const int* in_sizes, int n_in,
                              void* d_out, int out_size, void* d_ws, size_t ws_size,
                              hipStream_t stream) {
  (void)in_sizes; (void)n_in; (void)out_size; (void)ws_size;
  const float* orig  = (const float*)d_in[0];
  const int*   ridx  = (const int*)d_in[1];
  const float* embed = (const float*)d_in[2];
  const float* w0 = (const float*)d_in[3];  const float* b0 = (const float*)d_in[4];
  const float* w1 = (const float*)d_in[5];  const float* b1 = (const float*)d_in[6];
  const float* w2 = (const float*)d_in[7];  const float* b2 = (const float*)d_in[8];
  const float* w3 = (const float*)d_in[9];  const float* b3 = (const float*)d_in[10];
  const float* w4 = (const float*)d_in[11]; const float* b4 = (const float*)d_in[12];
  const float* w5 = (const float*)d_in[13]; const float* b5 = (const float*)d_in[14];
  const float* w6 = (const float*)d_in[15]; const float* b6 = (const float*)d_in[16];
  const float* rw0 = (const float*)d_in[17];
  const float* rw4 = (const float*)d_in[18];
  const float* rw6 = (const float*)d_in[19];
  const float* wout = (const float*)d_in[20];
  const float* bout = (const float*)d_in[21];

  // ws layout: gate 4MB | mmax 1MB | denom 1MB | packed weights ~7.3MB
  float*    gate   = (float*)d_ws;
  unsigned* mmax   = (unsigned*)((char*)d_ws + (size_t)4 * 1024 * 1024);
  float*    denom  = (float*)((char*)d_ws + (size_t)5 * 1024 * 1024);
  char*     packed = (char*)d_ws + (size_t)6 * 1024 * 1024;

  hipMemsetAsync(mmax, 0, (size_t)CC * 4 * sizeof(unsigned), stream);
  hipMemsetAsync(denom, 0, (size_t)CC * 4 * sizeof(float), stream);

  pack_kernel<<<dim3(44, 10, 4), 256, 0, stream>>>(
      w0, rw0, w1, w2, w3, w4, rw4, w5, w6, rw6, packed);

  hipFuncSetAttribute((const void*)mlp_kernel,
                      hipFuncAttributeMaxDynamicSharedMemorySize, 131072);
  mlp_kernel<<<NN / TM, BLK, 131072, stream>>>(
      orig, ridx, embed, packed,
      b0, b1, b2, b3, b4, b5, b6, wout, bout, gate, mmax);

  sm_pass2<<<NN * 4 / BLK, BLK, 0, stream>>>(ridx, mmax, gate, denom);
  sm_finalize<<<NN / BLK, BLK, 0, stream>>>(ridx, gate, denom, (float*)d_out);
}